// Round 1
// baseline (3069.868 us; speedup 1.0000x reference)
//
#include <hip/hip_runtime.h>

#define NODES  100000
#define EDGES  1600000
#define GRAPHS 4096
#define HID    128
#define INDIM  14

// ---------------- layer-1 aggregation (14-dim) ----------------

__global__ void k_init_pre1(const float* __restrict__ x, float* __restrict__ P) {
    int i = blockIdx.x * 256 + threadIdx.x;
    if (i < NODES * INDIM) P[i] = x[i];
}

__global__ void k_scatter14(const float* __restrict__ x, const int* __restrict__ src,
                            const int* __restrict__ dst, float* __restrict__ P) {
    int idx = blockIdx.x * 256 + threadIdx.x;
    int e = idx >> 4, d = idx & 15;
    if (e >= EDGES || d >= INDIM) return;
    atomicAdd(&P[dst[e] * INDIM + d], x[src[e] * INDIM + d]);
}

// ---------------- GEMMs ----------------

// out[row][0..127] = relu(in[row][0..13] @ W + b), thread = (row, 4 cols)
__global__ __launch_bounds__(256) void k_gemm14_relu(const float* __restrict__ in,
                                                     const float* __restrict__ W,
                                                     const float* __restrict__ b,
                                                     float* __restrict__ out) {
    int idx = blockIdx.x * 256 + threadIdx.x;
    int row = idx >> 5, c4 = (idx & 31) << 2;
    if (row >= NODES) return;
    const float4 bv = *(const float4*)&b[c4];
    float ax = bv.x, ay = bv.y, az = bv.z, aw = bv.w;
#pragma unroll
    for (int k = 0; k < INDIM; k++) {
        float a = in[row * INDIM + k];
        float4 w = *(const float4*)&W[k * HID + c4];
        ax += a * w.x; ay += a * w.y; az += a * w.z; aw += a * w.w;
    }
    float4 o = make_float4(fmaxf(ax, 0.f), fmaxf(ay, 0.f), fmaxf(az, 0.f), fmaxf(aw, 0.f));
    *(float4*)&out[(size_t)row * HID + c4] = o;
}

// out[M][128] = act(in[M][128] @ W[128][128] + b); 64 rows/block, 256 threads.
// Thread (rg = tid>>5 in {0..7}, cg = tid&31): computes rows {rg, rg+8, ..} x 4 cols.
template <int RELU>
__global__ __launch_bounds__(256) void k_gemm128(const float* __restrict__ in,
                                                 const float* __restrict__ W,
                                                 const float* __restrict__ b,
                                                 float* __restrict__ out, int M) {
    __shared__ float tile[64 * 132];  // padded stride: 132 floats
    const int tid = threadIdx.x;
    const int row0 = blockIdx.x * 64;

    for (int i = tid; i < 64 * 32; i += 256) {
        int r = i >> 5, c4 = (i & 31) << 2;
        float4 v = make_float4(0.f, 0.f, 0.f, 0.f);
        if (row0 + r < M) v = *(const float4*)&in[(size_t)(row0 + r) * HID + c4];
        *(float4*)&tile[r * 132 + c4] = v;
    }
    __syncthreads();

    const int cg = (tid & 31) << 2;
    const int rg = tid >> 5;
    const float4 bv = *(const float4*)&b[cg];
    float acc[8][4];
#pragma unroll
    for (int r = 0; r < 8; r++) {
        acc[r][0] = bv.x; acc[r][1] = bv.y; acc[r][2] = bv.z; acc[r][3] = bv.w;
    }
    for (int k = 0; k < HID; k++) {
        float4 w = *(const float4*)&W[k * HID + cg];
#pragma unroll
        for (int r = 0; r < 8; r++) {
            float a = tile[(r * 8 + rg) * 132 + k];
            acc[r][0] += a * w.x; acc[r][1] += a * w.y;
            acc[r][2] += a * w.z; acc[r][3] += a * w.w;
        }
    }
#pragma unroll
    for (int r = 0; r < 8; r++) {
        int row = row0 + r * 8 + rg;
        if (row < M) {
            float4 o;
            o.x = RELU ? fmaxf(acc[r][0], 0.f) : acc[r][0];
            o.y = RELU ? fmaxf(acc[r][1], 0.f) : acc[r][1];
            o.z = RELU ? fmaxf(acc[r][2], 0.f) : acc[r][2];
            o.w = RELU ? fmaxf(acc[r][3], 0.f) : acc[r][3];
            *(float4*)&out[(size_t)row * HID + cg] = o;
        }
    }
}

// ---------------- layer-2 aggregation (128-dim) ----------------

__global__ void k_copy4(const float4* __restrict__ s, float4* __restrict__ d, int n4) {
    int i = blockIdx.x * 256 + threadIdx.x;
    if (i < n4) d[i] = s[i];
}

__global__ void k_scatter128(const float* __restrict__ H, const int* __restrict__ src,
                             const int* __restrict__ dst, float* __restrict__ P) {
    int idx = blockIdx.x * 256 + threadIdx.x;
    int e = idx >> 5;
    int c4 = (idx & 31) << 2;
    if (e >= EDGES) return;
    int s = src[e], d = dst[e];
    float4 v = *(const float4*)&H[(size_t)s * HID + c4];
    float* p = &P[(size_t)d * HID + c4];
    atomicAdd(p + 0, v.x);
    atomicAdd(p + 1, v.y);
    atomicAdd(p + 2, v.z);
    atomicAdd(p + 3, v.w);
}

// ---------------- mean pool over sorted batch ----------------

__device__ __forceinline__ int lower_bound_i(const int* __restrict__ a, int n, int key) {
    int lo = 0, hi = n;
    while (lo < hi) {
        int mid = (lo + hi) >> 1;
        if (a[mid] < key) lo = mid + 1; else hi = mid;
    }
    return lo;
}

__global__ __launch_bounds__(128) void k_pool(const float* __restrict__ H,
                                              const int* __restrict__ batch,
                                              float* __restrict__ pooled) {
    int g = blockIdx.x;
    int d = threadIdx.x;
    int lo = lower_bound_i(batch, NODES, g);
    int hi = lower_bound_i(batch, NODES, g + 1);
    float acc = 0.f;
    for (int i = lo; i < hi; i++) acc += H[(size_t)i * HID + d];
    float cnt = (float)(hi - lo);
    pooled[(size_t)g * HID + d] = acc / fmaxf(cnt, 1.0f);
}

// ---------------- launch ----------------

extern "C" void kernel_launch(void* const* d_in, const int* in_sizes, int n_in,
                              void* d_out, int out_size, void* d_ws, size_t ws_size,
                              hipStream_t stream) {
    const float* x     = (const float*)d_in[0];
    const int*   ei    = (const int*)d_in[1];
    const int*   batch = (const int*)d_in[2];
    const float* W1a = (const float*)d_in[3];
    const float* b1a = (const float*)d_in[4];
    const float* W1b = (const float*)d_in[5];
    const float* b1b = (const float*)d_in[6];
    const float* W2a = (const float*)d_in[7];
    const float* b2a = (const float*)d_in[8];
    const float* W2b = (const float*)d_in[9];
    const float* b2b = (const float*)d_in[10];
    const float* Wout = (const float*)d_in[11];
    const float* bout = (const float*)d_in[12];

    const int* src = ei;
    const int* dst = ei + EDGES;

    float* A = (float*)d_ws;                       // NODES*HID floats
    float* B = A + (size_t)NODES * HID;            // NODES*HID floats
    float* pooled = B + (size_t)NODES * HID;       // GRAPHS*HID floats
    float* out = (float*)d_out;

    const int nb_gemm = (NODES + 63) / 64;  // 1563

    // ---- layer 1 ----
    // A[:NODES*14] = x ; A += scatter(x)
    k_init_pre1<<<(NODES * INDIM + 255) / 256, 256, 0, stream>>>(x, A);
    k_scatter14<<<(EDGES * 16) / 256, 256, 0, stream>>>(x, src, dst, A);
    // B = relu(A @ W1a + b1a)   (K=14)
    k_gemm14_relu<<<(NODES * 32) / 256, 256, 0, stream>>>(A, W1a, b1a, B);
    // A = relu(B @ W1b + b1b)   -> h1
    k_gemm128<1><<<nb_gemm, 256, 0, stream>>>(B, W1b, b1b, A, NODES);

    // ---- layer 2 ----
    // B = A ; B += scatter(A)
    k_copy4<<<(NODES * HID / 4 + 255) / 256, 256, 0, stream>>>((const float4*)A, (float4*)B,
                                                               NODES * HID / 4);
    k_scatter128<<<(EDGES * 32) / 256, 256, 0, stream>>>(A, src, dst, B);
    // A = relu(B @ W2a + b2a)
    k_gemm128<1><<<nb_gemm, 256, 0, stream>>>(B, W2a, b2a, A, NODES);
    // B = relu(A @ W2b + b2b)   -> h2
    k_gemm128<1><<<nb_gemm, 256, 0, stream>>>(A, W2b, b2b, B, NODES);

    // ---- pool + head ----
    k_pool<<<GRAPHS, 128, 0, stream>>>(B, batch, pooled);
    k_gemm128<0><<<(GRAPHS + 63) / 64, 256, 0, stream>>>(pooled, Wout, bout, out, GRAPHS);
}

// Round 2
// 765.938 us; speedup vs baseline: 4.0080x; 4.0080x over previous
//
#include <hip/hip_runtime.h>

#define NODES  100000
#define EDGES  1600000
#define GRAPHS 4096
#define HID    128
#define INDIM  14

// ---------------- CSR build (per call; dst-sorted) ----------------

__global__ void k_zero_int(int* __restrict__ p, int n) {
    int i = blockIdx.x * 256 + threadIdx.x;
    if (i < n) p[i] = 0;
}

__global__ void k_hist(const int* __restrict__ dst, int* __restrict__ deg) {
    int e = blockIdx.x * 256 + threadIdx.x;
    if (e < EDGES) atomicAdd(&deg[dst[e]], 1);
}

// single-block exclusive scan of deg[NODES] -> off[NODES+1]
__global__ __launch_bounds__(1024) void k_scan(const int* __restrict__ deg, int* __restrict__ off) {
    __shared__ int part[1024];
    const int t = threadIdx.x;
    const int CH = (NODES + 1023) / 1024;  // 98
    const int base = t * CH;
    int s = 0;
    for (int i = 0; i < CH; i++) {
        int idx = base + i;
        if (idx < NODES) s += deg[idx];
    }
    part[t] = s;
    __syncthreads();
    for (int o = 1; o < 1024; o <<= 1) {
        int v = (t >= o) ? part[t - o] : 0;
        __syncthreads();
        part[t] += v;
        __syncthreads();
    }
    int run = (t == 0) ? 0 : part[t - 1];
    for (int i = 0; i < CH; i++) {
        int idx = base + i;
        if (idx < NODES) { off[idx] = run; run += deg[idx]; }
    }
    if (t == 1023) off[NODES] = EDGES;
}

__global__ void k_fill(const int* __restrict__ src, const int* __restrict__ dst,
                       const int* __restrict__ off, int* __restrict__ cnt,
                       int* __restrict__ csr) {
    int e = blockIdx.x * 256 + threadIdx.x;
    if (e >= EDGES) return;
    int d = dst[e];
    int pos = off[d] + atomicAdd(&cnt[d], 1);
    csr[pos] = src[e];
}

// ---------------- gather aggregation ----------------

// P[n][d] = x[n][d] + sum_{j in in(n)} x[j][d], d < 14. 16 threads/node.
__global__ void k_gather14(const float* __restrict__ x, const int* __restrict__ off,
                           const int* __restrict__ csr, float* __restrict__ P) {
    int idx = blockIdx.x * 256 + threadIdx.x;
    int n = idx >> 4, d = idx & 15;
    if (n >= NODES || d >= INDIM) return;
    int lo = off[n], hi = off[n + 1];
    float acc = x[n * INDIM + d];
    for (int e = lo; e < hi; e++) acc += x[csr[e] * INDIM + d];
    P[n * INDIM + d] = acc;
}

// Out[n][:] = H[n][:] + sum_{j in in(n)} H[j][:]. One wave (64 lanes x float2)/node.
__global__ __launch_bounds__(256) void k_gather128(const float2* __restrict__ H2,
                                                   const int* __restrict__ off,
                                                   const int* __restrict__ csr,
                                                   float2* __restrict__ Out2) {
    int wave = (blockIdx.x * 256 + threadIdx.x) >> 6;
    int lane = threadIdx.x & 63;
    if (wave >= NODES) return;
    int lo = off[wave], hi = off[wave + 1];
    float2 acc = H2[(size_t)wave * 64 + lane];
    int e = lo;
    for (; e + 1 < hi; e += 2) {
        int s0 = csr[e], s1 = csr[e + 1];
        float2 v0 = H2[(size_t)s0 * 64 + lane];
        float2 v1 = H2[(size_t)s1 * 64 + lane];
        acc.x += v0.x + v1.x;
        acc.y += v0.y + v1.y;
    }
    if (e < hi) {
        float2 v = H2[(size_t)csr[e] * 64 + lane];
        acc.x += v.x; acc.y += v.y;
    }
    Out2[(size_t)wave * 64 + lane] = acc;
}

// ---------------- GEMMs ----------------

__global__ __launch_bounds__(256) void k_gemm14_relu(const float* __restrict__ in,
                                                     const float* __restrict__ W,
                                                     const float* __restrict__ b,
                                                     float* __restrict__ out) {
    int idx = blockIdx.x * 256 + threadIdx.x;
    int row = idx >> 5, c4 = (idx & 31) << 2;
    if (row >= NODES) return;
    const float4 bv = *(const float4*)&b[c4];
    float ax = bv.x, ay = bv.y, az = bv.z, aw = bv.w;
#pragma unroll
    for (int k = 0; k < INDIM; k++) {
        float a = in[row * INDIM + k];
        float4 w = *(const float4*)&W[k * HID + c4];
        ax += a * w.x; ay += a * w.y; az += a * w.z; aw += a * w.w;
    }
    float4 o = make_float4(fmaxf(ax, 0.f), fmaxf(ay, 0.f), fmaxf(az, 0.f), fmaxf(aw, 0.f));
    *(float4*)&out[(size_t)row * HID + c4] = o;
}

template <int RELU>
__global__ __launch_bounds__(256) void k_gemm128(const float* __restrict__ in,
                                                 const float* __restrict__ W,
                                                 const float* __restrict__ b,
                                                 float* __restrict__ out, int M) {
    __shared__ float tile[64 * 132];
    const int tid = threadIdx.x;
    const int row0 = blockIdx.x * 64;

    for (int i = tid; i < 64 * 32; i += 256) {
        int r = i >> 5, c4 = (i & 31) << 2;
        float4 v = make_float4(0.f, 0.f, 0.f, 0.f);
        if (row0 + r < M) v = *(const float4*)&in[(size_t)(row0 + r) * HID + c4];
        *(float4*)&tile[r * 132 + c4] = v;
    }
    __syncthreads();

    const int cg = (tid & 31) << 2;
    const int rg = tid >> 5;
    const float4 bv = *(const float4*)&b[cg];
    float acc[8][4];
#pragma unroll
    for (int r = 0; r < 8; r++) {
        acc[r][0] = bv.x; acc[r][1] = bv.y; acc[r][2] = bv.z; acc[r][3] = bv.w;
    }
    for (int k = 0; k < HID; k++) {
        float4 w = *(const float4*)&W[k * HID + cg];
#pragma unroll
        for (int r = 0; r < 8; r++) {
            float a = tile[(r * 8 + rg) * 132 + k];
            acc[r][0] += a * w.x; acc[r][1] += a * w.y;
            acc[r][2] += a * w.z; acc[r][3] += a * w.w;
        }
    }
#pragma unroll
    for (int r = 0; r < 8; r++) {
        int row = row0 + r * 8 + rg;
        if (row < M) {
            float4 o;
            o.x = RELU ? fmaxf(acc[r][0], 0.f) : acc[r][0];
            o.y = RELU ? fmaxf(acc[r][1], 0.f) : acc[r][1];
            o.z = RELU ? fmaxf(acc[r][2], 0.f) : acc[r][2];
            o.w = RELU ? fmaxf(acc[r][3], 0.f) : acc[r][3];
            *(float4*)&out[(size_t)row * HID + cg] = o;
        }
    }
}

// ---------------- mean pool over sorted batch ----------------

__device__ __forceinline__ int lower_bound_i(const int* __restrict__ a, int n, int key) {
    int lo = 0, hi = n;
    while (lo < hi) {
        int mid = (lo + hi) >> 1;
        if (a[mid] < key) lo = mid + 1; else hi = mid;
    }
    return lo;
}

__global__ __launch_bounds__(128) void k_pool(const float* __restrict__ H,
                                              const int* __restrict__ batch,
                                              float* __restrict__ pooled) {
    int g = blockIdx.x;
    int d = threadIdx.x;
    int lo = lower_bound_i(batch, NODES, g);
    int hi = lower_bound_i(batch, NODES, g + 1);
    float acc = 0.f;
    for (int i = lo; i < hi; i++) acc += H[(size_t)i * HID + d];
    float cnt = (float)(hi - lo);
    pooled[(size_t)g * HID + d] = acc / fmaxf(cnt, 1.0f);
}

// ---------------- launch ----------------

extern "C" void kernel_launch(void* const* d_in, const int* in_sizes, int n_in,
                              void* d_out, int out_size, void* d_ws, size_t ws_size,
                              hipStream_t stream) {
    const float* x     = (const float*)d_in[0];
    const int*   ei    = (const int*)d_in[1];
    const int*   batch = (const int*)d_in[2];
    const float* W1a = (const float*)d_in[3];
    const float* b1a = (const float*)d_in[4];
    const float* W1b = (const float*)d_in[5];
    const float* b1b = (const float*)d_in[6];
    const float* W2a = (const float*)d_in[7];
    const float* b2a = (const float*)d_in[8];
    const float* W2b = (const float*)d_in[9];
    const float* b2b = (const float*)d_in[10];
    const float* Wout = (const float*)d_in[11];
    const float* bout = (const float*)d_in[12];

    const int* src = ei;
    const int* dst = ei + EDGES;

    float* A      = (float*)d_ws;                  // NODES*HID
    float* B      = A + (size_t)NODES * HID;       // NODES*HID
    float* pooled = B + (size_t)NODES * HID;       // GRAPHS*HID
    int* deg = (int*)(pooled + (size_t)GRAPHS * HID);  // NODES (also reused as fill cursor)
    int* off = deg + NODES;                        // NODES+1
    int* csr = off + NODES + 1;                    // EDGES
    float* out = (float*)d_out;

    const int nb_gemm = (NODES + 63) / 64;

    // ---- CSR build ----
    k_zero_int<<<(NODES + 255) / 256, 256, 0, stream>>>(deg, NODES);
    k_hist<<<(EDGES + 255) / 256, 256, 0, stream>>>(dst, deg);
    k_scan<<<1, 1024, 0, stream>>>(deg, off);
    k_zero_int<<<(NODES + 255) / 256, 256, 0, stream>>>(deg, NODES);  // reuse as cursor
    k_fill<<<(EDGES + 255) / 256, 256, 0, stream>>>(src, dst, off, deg, csr);

    // ---- layer 1 ----
    k_gather14<<<(NODES * 16 + 255) / 256, 256, 0, stream>>>(x, off, csr, A);
    k_gemm14_relu<<<(NODES * 32) / 256, 256, 0, stream>>>(A, W1a, b1a, B);
    k_gemm128<1><<<nb_gemm, 256, 0, stream>>>(B, W1b, b1b, A, NODES);  // h1 -> A

    // ---- layer 2 ----
    k_gather128<<<(NODES + 3) / 4, 256, 0, stream>>>((const float2*)A, off, csr, (float2*)B);
    k_gemm128<1><<<nb_gemm, 256, 0, stream>>>(B, W2a, b2a, A, NODES);
    k_gemm128<1><<<nb_gemm, 256, 0, stream>>>(A, W2b, b2b, B, NODES);  // h2 -> B

    // ---- pool + head ----
    k_pool<<<GRAPHS, 128, 0, stream>>>(B, batch, pooled);
    k_gemm128<0><<<(GRAPHS + 63) / 64, 256, 0, stream>>>(pooled, Wout, bout, out, GRAPHS);
}

// Round 3
// 604.022 us; speedup vs baseline: 5.0824x; 1.2681x over previous
//
#include <hip/hip_runtime.h>

#define NODES  100000
#define EDGES  1600000
#define GRAPHS 4096
#define HID    128
#define INDIM  14
#define SCAN_BLK ((NODES + 1023) / 1024)  // 98

// ---------------- CSR build (per call; dst-CSR) ----------------

__global__ void k_zero_int(int* __restrict__ p, int n) {
    int i = blockIdx.x * 256 + threadIdx.x;
    if (i < n) p[i] = 0;
}

__global__ void k_hist(const int* __restrict__ dst, int* __restrict__ deg) {
    int e = blockIdx.x * 256 + threadIdx.x;
    if (e < EDGES) atomicAdd(&deg[dst[e]], 1);
}

// partials[b] = sum of deg over block b's 1024 elements
__global__ __launch_bounds__(1024) void k_scan1(const int* __restrict__ deg,
                                                int* __restrict__ partials) {
    __shared__ int s[1024];
    int t = threadIdx.x;
    int i = blockIdx.x * 1024 + t;
    s[t] = (i < NODES) ? deg[i] : 0;
    __syncthreads();
    for (int o = 512; o > 0; o >>= 1) {
        if (t < o) s[t] += s[t + o];
        __syncthreads();
    }
    if (t == 0) partials[blockIdx.x] = s[0];
}

// pref[b] = exclusive prefix of partials (SCAN_BLK <= 128)
__global__ __launch_bounds__(128) void k_scan2(const int* __restrict__ partials,
                                               int* __restrict__ pref) {
    __shared__ int s[128];
    int t = threadIdx.x;
    int v = (t < SCAN_BLK) ? partials[t] : 0;
    s[t] = v;
    __syncthreads();
    for (int o = 1; o < 128; o <<= 1) {
        int u = (t >= o) ? s[t - o] : 0;
        __syncthreads();
        s[t] += u;
        __syncthreads();
    }
    if (t < SCAN_BLK) pref[t] = s[t] - v;
}

// off[i] = pref[blk] + intra-block exclusive scan
__global__ __launch_bounds__(1024) void k_scan3(const int* __restrict__ deg,
                                                const int* __restrict__ pref,
                                                int* __restrict__ off) {
    __shared__ int s[1024];
    int t = threadIdx.x;
    int i = blockIdx.x * 1024 + t;
    int v = (i < NODES) ? deg[i] : 0;
    s[t] = v;
    __syncthreads();
    for (int o = 1; o < 1024; o <<= 1) {
        int u = (t >= o) ? s[t - o] : 0;
        __syncthreads();
        s[t] += u;
        __syncthreads();
    }
    if (i < NODES) off[i] = pref[blockIdx.x] + s[t] - v;
    if (blockIdx.x == 0 && t == 0) off[NODES] = EDGES;
}

__global__ void k_fill(const int* __restrict__ src, const int* __restrict__ dst,
                       const int* __restrict__ off, int* __restrict__ cnt,
                       int* __restrict__ csr) {
    int e = blockIdx.x * 256 + threadIdx.x;
    if (e >= EDGES) return;
    int d = dst[e];
    int pos = off[d] + atomicAdd(&cnt[d], 1);
    csr[pos] = src[e];
}

// ---------------- gather aggregation ----------------

__global__ void k_gather14(const float* __restrict__ x, const int* __restrict__ off,
                           const int* __restrict__ csr, float* __restrict__ P) {
    int idx = blockIdx.x * 256 + threadIdx.x;
    int n = idx >> 4, d = idx & 15;
    if (n >= NODES || d >= INDIM) return;
    int lo = off[n], hi = off[n + 1];
    float acc = x[n * INDIM + d];
    for (int e = lo; e < hi; e++) acc += x[csr[e] * INDIM + d];
    P[n * INDIM + d] = acc;
}

__global__ __launch_bounds__(256) void k_gather128(const float2* __restrict__ H2,
                                                   const int* __restrict__ off,
                                                   const int* __restrict__ csr,
                                                   float2* __restrict__ Out2) {
    int wave = (blockIdx.x * 256 + threadIdx.x) >> 6;
    int lane = threadIdx.x & 63;
    if (wave >= NODES) return;
    int lo = off[wave], hi = off[wave + 1];
    float2 acc = H2[(size_t)wave * 64 + lane];
    int e = lo;
    for (; e + 1 < hi; e += 2) {
        int s0 = csr[e], s1 = csr[e + 1];
        float2 v0 = H2[(size_t)s0 * 64 + lane];
        float2 v1 = H2[(size_t)s1 * 64 + lane];
        acc.x += v0.x + v1.x;
        acc.y += v0.y + v1.y;
    }
    if (e < hi) {
        float2 v = H2[(size_t)csr[e] * 64 + lane];
        acc.x += v.x; acc.y += v.y;
    }
    Out2[(size_t)wave * 64 + lane] = acc;
}

// ---------------- GEMMs ----------------

__global__ __launch_bounds__(256) void k_gemm14_relu(const float* __restrict__ in,
                                                     const float* __restrict__ W,
                                                     const float* __restrict__ b,
                                                     float* __restrict__ out) {
    int idx = blockIdx.x * 256 + threadIdx.x;
    int row = idx >> 5, c4 = (idx & 31) << 2;
    if (row >= NODES) return;
    const float4 bv = *(const float4*)&b[c4];
    float ax = bv.x, ay = bv.y, az = bv.z, aw = bv.w;
#pragma unroll
    for (int k = 0; k < INDIM; k++) {
        float a = in[row * INDIM + k];
        float4 w = *(const float4*)&W[k * HID + c4];
        ax += a * w.x; ay += a * w.y; az += a * w.z; aw += a * w.w;
    }
    float4 o = make_float4(fmaxf(ax, 0.f), fmaxf(ay, 0.f), fmaxf(az, 0.f), fmaxf(aw, 0.f));
    *(float4*)&out[(size_t)row * HID + c4] = o;
}

// 64 rows/block, 256 threads; thread (rg=tid>>5, cg=tid&31): 8 rows x 4 cols.
// A staged in LDS with stride 136 (16B-aligned float4 reads, wave-broadcast).
template <int RELU>
__global__ __launch_bounds__(256) void k_gemm128(const float* __restrict__ in,
                                                 const float* __restrict__ W,
                                                 const float* __restrict__ b,
                                                 float* __restrict__ out, int M) {
    __shared__ float tile[64 * 136];
    const int tid = threadIdx.x;
    const int row0 = blockIdx.x * 64;

    for (int i = tid; i < 64 * 32; i += 256) {
        int r = i >> 5, c4 = (i & 31) << 2;
        float4 v = make_float4(0.f, 0.f, 0.f, 0.f);
        if (row0 + r < M) v = *(const float4*)&in[(size_t)(row0 + r) * HID + c4];
        *(float4*)&tile[r * 136 + c4] = v;
    }
    __syncthreads();

    const int cg = (tid & 31) << 2;
    const int rg = tid >> 5;
    const float4 bv = *(const float4*)&b[cg];
    float acc[8][4];
#pragma unroll
    for (int r = 0; r < 8; r++) {
        acc[r][0] = bv.x; acc[r][1] = bv.y; acc[r][2] = bv.z; acc[r][3] = bv.w;
    }
    for (int k0 = 0; k0 < HID; k0 += 4) {
        float4 w0 = *(const float4*)&W[(k0 + 0) * HID + cg];
        float4 w1 = *(const float4*)&W[(k0 + 1) * HID + cg];
        float4 w2 = *(const float4*)&W[(k0 + 2) * HID + cg];
        float4 w3 = *(const float4*)&W[(k0 + 3) * HID + cg];
#pragma unroll
        for (int r = 0; r < 8; r++) {
            float4 a = *(const float4*)&tile[(r * 8 + rg) * 136 + k0];
            acc[r][0] += a.x * w0.x + a.y * w1.x + a.z * w2.x + a.w * w3.x;
            acc[r][1] += a.x * w0.y + a.y * w1.y + a.z * w2.y + a.w * w3.y;
            acc[r][2] += a.x * w0.z + a.y * w1.z + a.z * w2.z + a.w * w3.z;
            acc[r][3] += a.x * w0.w + a.y * w1.w + a.z * w2.w + a.w * w3.w;
        }
    }
#pragma unroll
    for (int r = 0; r < 8; r++) {
        int row = row0 + r * 8 + rg;
        if (row < M) {
            float4 o;
            o.x = RELU ? fmaxf(acc[r][0], 0.f) : acc[r][0];
            o.y = RELU ? fmaxf(acc[r][1], 0.f) : acc[r][1];
            o.z = RELU ? fmaxf(acc[r][2], 0.f) : acc[r][2];
            o.w = RELU ? fmaxf(acc[r][3], 0.f) : acc[r][3];
            *(float4*)&out[(size_t)row * HID + cg] = o;
        }
    }
}

// head: out[4096][128] = pooled @ Wout + bout; 8 rows/block, 512 blocks.
__global__ __launch_bounds__(256) void k_gemm_head(const float* __restrict__ in,
                                                   const float* __restrict__ W,
                                                   const float* __restrict__ b,
                                                   float* __restrict__ out) {
    int idx = blockIdx.x * 256 + threadIdx.x;
    int row = idx >> 5, c4 = (idx & 31) << 2;
    if (row >= GRAPHS) return;
    const float4 bv = *(const float4*)&b[c4];
    float4 acc = bv;
    for (int k0 = 0; k0 < HID; k0 += 4) {
        float4 a = *(const float4*)&in[(size_t)row * HID + k0];
        float4 w0 = *(const float4*)&W[(k0 + 0) * HID + c4];
        float4 w1 = *(const float4*)&W[(k0 + 1) * HID + c4];
        float4 w2 = *(const float4*)&W[(k0 + 2) * HID + c4];
        float4 w3 = *(const float4*)&W[(k0 + 3) * HID + c4];
        acc.x += a.x * w0.x + a.y * w1.x + a.z * w2.x + a.w * w3.x;
        acc.y += a.x * w0.y + a.y * w1.y + a.z * w2.y + a.w * w3.y;
        acc.z += a.x * w0.z + a.y * w1.z + a.z * w2.z + a.w * w3.z;
        acc.w += a.x * w0.w + a.y * w1.w + a.z * w2.w + a.w * w3.w;
    }
    *(float4*)&out[(size_t)row * HID + c4] = acc;
}

// ---------------- mean pool over sorted batch ----------------

__device__ __forceinline__ int lower_bound_i(const int* __restrict__ a, int n, int key) {
    int lo = 0, hi = n;
    while (lo < hi) {
        int mid = (lo + hi) >> 1;
        if (a[mid] < key) lo = mid + 1; else hi = mid;
    }
    return lo;
}

__global__ __launch_bounds__(128) void k_pool(const float* __restrict__ H,
                                              const int* __restrict__ batch,
                                              float* __restrict__ pooled) {
    int g = blockIdx.x;
    int d = threadIdx.x;
    int lo = lower_bound_i(batch, NODES, g);
    int hi = lower_bound_i(batch, NODES, g + 1);
    float acc = 0.f;
    for (int i = lo; i < hi; i++) acc += H[(size_t)i * HID + d];
    float cnt = (float)(hi - lo);
    pooled[(size_t)g * HID + d] = acc / fmaxf(cnt, 1.0f);
}

// ---------------- launch ----------------

extern "C" void kernel_launch(void* const* d_in, const int* in_sizes, int n_in,
                              void* d_out, int out_size, void* d_ws, size_t ws_size,
                              hipStream_t stream) {
    const float* x     = (const float*)d_in[0];
    const int*   ei    = (const int*)d_in[1];
    const int*   batch = (const int*)d_in[2];
    const float* W1a = (const float*)d_in[3];
    const float* b1a = (const float*)d_in[4];
    const float* W1b = (const float*)d_in[5];
    const float* b1b = (const float*)d_in[6];
    const float* W2a = (const float*)d_in[7];
    const float* b2a = (const float*)d_in[8];
    const float* W2b = (const float*)d_in[9];
    const float* b2b = (const float*)d_in[10];
    const float* Wout = (const float*)d_in[11];
    const float* bout = (const float*)d_in[12];

    const int* src = ei;
    const int* dst = ei + EDGES;

    float* A      = (float*)d_ws;                       // NODES*HID
    float* B      = A + (size_t)NODES * HID;            // NODES*HID
    float* pooled = B + (size_t)NODES * HID;            // GRAPHS*HID
    int* deg = (int*)(pooled + (size_t)GRAPHS * HID);   // NODES (reused as cursor)
    int* off = deg + NODES;                             // NODES+1
    int* csr = off + NODES + 1;                         // EDGES
    int* partials = csr + EDGES;                        // SCAN_BLK
    int* pref = partials + SCAN_BLK;                    // SCAN_BLK
    float* out = (float*)d_out;

    const int nb_gemm = (NODES + 63) / 64;

    // ---- CSR build ----
    k_zero_int<<<(NODES + 255) / 256, 256, 0, stream>>>(deg, NODES);
    k_hist<<<(EDGES + 255) / 256, 256, 0, stream>>>(dst, deg);
    k_scan1<<<SCAN_BLK, 1024, 0, stream>>>(deg, partials);
    k_scan2<<<1, 128, 0, stream>>>(partials, pref);
    k_scan3<<<SCAN_BLK, 1024, 0, stream>>>(deg, pref, off);
    k_zero_int<<<(NODES + 255) / 256, 256, 0, stream>>>(deg, NODES);  // cursor
    k_fill<<<(EDGES + 255) / 256, 256, 0, stream>>>(src, dst, off, deg, csr);

    // ---- layer 1 ----
    k_gather14<<<(NODES * 16 + 255) / 256, 256, 0, stream>>>(x, off, csr, A);
    k_gemm14_relu<<<(NODES * 32) / 256, 256, 0, stream>>>(A, W1a, b1a, B);
    k_gemm128<1><<<nb_gemm, 256, 0, stream>>>(B, W1b, b1b, A, NODES);  // h1 -> A

    // ---- layer 2 ----
    k_gather128<<<(NODES + 3) / 4, 256, 0, stream>>>((const float2*)A, off, csr, (float2*)B);
    k_gemm128<1><<<nb_gemm, 256, 0, stream>>>(B, W2a, b2a, A, NODES);
    k_gemm128<1><<<nb_gemm, 256, 0, stream>>>(A, W2b, b2b, B, NODES);  // h2 -> B

    // ---- pool + head ----
    k_pool<<<GRAPHS, 128, 0, stream>>>(B, batch, pooled);
    k_gemm_head<<<(GRAPHS * 32) / 256, 256, 0, stream>>>(pooled, Wout, bout, out);
}

// Round 5
// 497.160 us; speedup vs baseline: 6.1748x; 1.2149x over previous
//
#include <hip/hip_runtime.h>
#include <hip/hip_bf16.h>

#define NODES  100000
#define EDGES  1600000
#define GRAPHS 4096
#define HID    128
#define INDIM  14
#define SCAN_BLK ((NODES + 1023) / 1024)  // 98

typedef float f32x4 __attribute__((ext_vector_type(4)));
typedef short bf16x8 __attribute__((ext_vector_type(8)));

__device__ __forceinline__ unsigned packbf(float a, float b) {
    __hip_bfloat162 t;
    t.x = __float2bfloat16(a);
    t.y = __float2bfloat16(b);
    return *(unsigned*)&t;
}
__device__ __forceinline__ float2 upk(unsigned u) {
    float2 f;
    f.x = __uint_as_float(u << 16);
    f.y = __uint_as_float(u & 0xffff0000u);
    return f;
}

// ---------------- CSR build ----------------

__global__ void k_zero_int(int* __restrict__ p, int n) {
    int i = blockIdx.x * 256 + threadIdx.x;
    if (i < n) p[i] = 0;
}

__global__ void k_hist(const int* __restrict__ dst, int* __restrict__ deg) {
    int e = blockIdx.x * 256 + threadIdx.x;
    if (e < EDGES) atomicAdd(&deg[dst[e]], 1);
}

__global__ __launch_bounds__(1024) void k_scan1(const int* __restrict__ deg,
                                                int* __restrict__ partials) {
    __shared__ int s[1024];
    int t = threadIdx.x;
    int i = blockIdx.x * 1024 + t;
    s[t] = (i < NODES) ? deg[i] : 0;
    __syncthreads();
    for (int o = 512; o > 0; o >>= 1) {
        if (t < o) s[t] += s[t + o];
        __syncthreads();
    }
    if (t == 0) partials[blockIdx.x] = s[0];
}

__global__ __launch_bounds__(128) void k_scan2(const int* __restrict__ partials,
                                               int* __restrict__ pref) {
    __shared__ int s[128];
    int t = threadIdx.x;
    int v = (t < SCAN_BLK) ? partials[t] : 0;
    s[t] = v;
    __syncthreads();
    for (int o = 1; o < 128; o <<= 1) {
        int u = (t >= o) ? s[t - o] : 0;
        __syncthreads();
        s[t] += u;
        __syncthreads();
    }
    if (t < SCAN_BLK) pref[t] = s[t] - v;
}

__global__ __launch_bounds__(1024) void k_scan3(const int* __restrict__ deg,
                                                const int* __restrict__ pref,
                                                int* __restrict__ off) {
    __shared__ int s[1024];
    int t = threadIdx.x;
    int i = blockIdx.x * 1024 + t;
    int v = (i < NODES) ? deg[i] : 0;
    s[t] = v;
    __syncthreads();
    for (int o = 1; o < 1024; o <<= 1) {
        int u = (t >= o) ? s[t - o] : 0;
        __syncthreads();
        s[t] += u;
        __syncthreads();
    }
    if (i < NODES) off[i] = pref[blockIdx.x] + s[t] - v;
    if (blockIdx.x == 0 && t == 0) off[NODES] = EDGES;
}

__global__ void k_fill(const int* __restrict__ src, const int* __restrict__ dst,
                       const int* __restrict__ off, int* __restrict__ cnt,
                       int* __restrict__ csr) {
    int e = blockIdx.x * 256 + threadIdx.x;
    if (e >= EDGES) return;
    int d = dst[e];
    int pos = off[d] + atomicAdd(&cnt[d], 1);
    csr[pos] = src[e];
}

// ---------------- weight convert: W[k][n] fp32 -> Wt[n][k] bf16 ----------------

__global__ void k_w_cvt(const float* __restrict__ W, __hip_bfloat16* __restrict__ Wt) {
    int idx = blockIdx.x * 256 + threadIdx.x;  // 16384
    int n = idx & 127, k = idx >> 7;
    Wt[n * HID + k] = __float2bfloat16(W[k * HID + n]);
}

// ---------------- aggregation ----------------

__global__ void k_gather14(const float* __restrict__ x, const int* __restrict__ off,
                           const int* __restrict__ csr, float* __restrict__ P) {
    int idx = blockIdx.x * 256 + threadIdx.x;
    int n = idx >> 4, d = idx & 15;
    if (n >= NODES || d >= INDIM) return;
    int lo = off[n], hi = off[n + 1];
    float acc = x[n * INDIM + d];
    for (int e = lo; e < hi; e++) acc += x[csr[e] * INDIM + d];
    P[n * INDIM + d] = acc;
}

// bf16 rows: H is [NODES][64] uints (2 bf16 each). One wave per node, fp32 accum.
__global__ __launch_bounds__(256) void k_gather128_bf(const unsigned* __restrict__ H,
                                                      const int* __restrict__ off,
                                                      const int* __restrict__ csr,
                                                      unsigned* __restrict__ Out) {
    int node = (blockIdx.x * 256 + threadIdx.x) >> 6;
    int lane = threadIdx.x & 63;
    if (node >= NODES) return;
    int lo = off[node], hi = off[node + 1];
    float2 acc = upk(H[(size_t)node * 64 + lane]);
    int e = lo;
    for (; e + 1 < hi; e += 2) {
        int s0 = csr[e], s1 = csr[e + 1];
        float2 v0 = upk(H[(size_t)s0 * 64 + lane]);
        float2 v1 = upk(H[(size_t)s1 * 64 + lane]);
        acc.x += v0.x + v1.x;
        acc.y += v0.y + v1.y;
    }
    if (e < hi) {
        float2 v = upk(H[(size_t)csr[e] * 64 + lane]);
        acc.x += v.x; acc.y += v.y;
    }
    Out[(size_t)node * 64 + lane] = packbf(acc.x, acc.y);
}

// ---------------- layer-1 input GEMM (K=14, fp32 in, bf16 out) ----------------

__global__ __launch_bounds__(256) void k_gemm14_relu(const float* __restrict__ in,
                                                     const float* __restrict__ W,
                                                     const float* __restrict__ b,
                                                     unsigned* __restrict__ out) {
    int idx = blockIdx.x * 256 + threadIdx.x;
    int row = idx >> 5, c4 = (idx & 31) << 2;
    if (row >= NODES) return;
    const float4 bv = *(const float4*)&b[c4];
    float ax = bv.x, ay = bv.y, az = bv.z, aw = bv.w;
#pragma unroll
    for (int k = 0; k < INDIM; k++) {
        float a = in[row * INDIM + k];
        float4 w = *(const float4*)&W[k * HID + c4];
        ax += a * w.x; ay += a * w.y; az += a * w.z; aw += a * w.w;
    }
    unsigned p0 = packbf(fmaxf(ax, 0.f), fmaxf(ay, 0.f));
    unsigned p1 = packbf(fmaxf(az, 0.f), fmaxf(aw, 0.f));
    // FIX (R4 bug): row stride is 64 uints (128 bf16), was 32 -> rows overlapped.
    *(uint2*)&out[(size_t)row * 64 + (c4 >> 1)] = make_uint2(p0, p1);
}

// ---------------- MFMA GEMM: [M][128] bf16 @ Wt[n][k] bf16 + bias -> out ----------------
// Block = 4 waves; wave computes 16 rows x 128 cols via 8 N-frags x 4 K-chunks.
// A frag: lane holds A[row0+(l&15)][kc*32 + (l>>4)*8 .. +7] (contiguous 16B).
// B frag: lane holds W[k][n*16+(l&15)] = Wt[n*16+(l&15)][kc*32 + (l>>4)*8 .. +7].
// C/D: col = lane&15, row = (lane>>4)*4 + reg  [verified mapping].
template <int RELU, int OUT_BF16>
__global__ __launch_bounds__(256) void k_mfma_gemm(const __hip_bfloat16* __restrict__ A,
                                                   const __hip_bfloat16* __restrict__ Wt,
                                                   const float* __restrict__ bias,
                                                   void* __restrict__ outv, int M) {
    const int wave = threadIdx.x >> 6;
    const int lane = threadIdx.x & 63;
    const int row0 = blockIdx.x * 64 + wave * 16;
    const int rl = lane & 15;
    const int kb = lane >> 4;  // 0..3

    int arow = row0 + rl;
    if (arow > M - 1) arow = M - 1;
    const __hip_bfloat16* Ap = A + (size_t)arow * HID + kb * 8;
    bf16x8 afrag[4];
#pragma unroll
    for (int kc = 0; kc < 4; kc++) afrag[kc] = *(const bf16x8*)(Ap + kc * 32);

    f32x4 acc[8];
#pragma unroll
    for (int n = 0; n < 8; n++) acc[n] = (f32x4){0.f, 0.f, 0.f, 0.f};

#pragma unroll
    for (int n = 0; n < 8; n++) {
        const __hip_bfloat16* Bp = Wt + (size_t)(n * 16 + rl) * HID + kb * 8;
#pragma unroll
        for (int kc = 0; kc < 4; kc++) {
            bf16x8 bfrag = *(const bf16x8*)(Bp + kc * 32);
            acc[n] = __builtin_amdgcn_mfma_f32_16x16x32_bf16(afrag[kc], bfrag, acc[n], 0, 0, 0);
        }
    }

#pragma unroll
    for (int n = 0; n < 8; n++) {
        const int col = n * 16 + rl;
        const float bv = bias[col];
#pragma unroll
        for (int j = 0; j < 4; j++) {
            int row = row0 + kb * 4 + j;
            if (row < M) {
                float v = acc[n][j] + bv;
                if (RELU) v = fmaxf(v, 0.f);
                if (OUT_BF16)
                    ((__hip_bfloat16*)outv)[(size_t)row * HID + col] = __float2bfloat16(v);
                else
                    ((float*)outv)[(size_t)row * HID + col] = v;
            }
        }
    }
}

// ---------------- mean pool (bf16 in, bf16 out) ----------------

__device__ __forceinline__ int lower_bound_i(const int* __restrict__ a, int n, int key) {
    int lo = 0, hi = n;
    while (lo < hi) {
        int mid = (lo + hi) >> 1;
        if (a[mid] < key) lo = mid + 1; else hi = mid;
    }
    return lo;
}

__global__ __launch_bounds__(128) void k_pool(const __hip_bfloat16* __restrict__ H,
                                              const int* __restrict__ batch,
                                              __hip_bfloat16* __restrict__ pooled) {
    int g = blockIdx.x;
    int d = threadIdx.x;
    int lo = lower_bound_i(batch, NODES, g);
    int hi = lower_bound_i(batch, NODES, g + 1);
    float acc = 0.f;
    for (int i = lo; i < hi; i++) acc += __bfloat162float(H[(size_t)i * HID + d]);
    float cnt = (float)(hi - lo);
    pooled[(size_t)g * HID + d] = __float2bfloat16(acc / fmaxf(cnt, 1.0f));
}

// ---------------- launch ----------------

extern "C" void kernel_launch(void* const* d_in, const int* in_sizes, int n_in,
                              void* d_out, int out_size, void* d_ws, size_t ws_size,
                              hipStream_t stream) {
    const float* x     = (const float*)d_in[0];
    const int*   ei    = (const int*)d_in[1];
    const int*   batch = (const int*)d_in[2];
    const float* W1a = (const float*)d_in[3];
    const float* b1a = (const float*)d_in[4];
    const float* W1b = (const float*)d_in[5];
    const float* b1b = (const float*)d_in[6];
    const float* W2a = (const float*)d_in[7];
    const float* b2a = (const float*)d_in[8];
    const float* W2b = (const float*)d_in[9];
    const float* b2b = (const float*)d_in[10];
    const float* Wout = (const float*)d_in[11];
    const float* bout = (const float*)d_in[12];

    const int* src = ei;
    const int* dst = ei + EDGES;

    char* w = (char*)d_ws;
    auto alloc = [&](size_t bytes) {
        void* p = (void*)w;
        w += (bytes + 255) & ~(size_t)255;
        return p;
    };
    __hip_bfloat16* Abf = (__hip_bfloat16*)alloc((size_t)NODES * HID * 2);
    __hip_bfloat16* Bbf = (__hip_bfloat16*)alloc((size_t)NODES * HID * 2);
    float* P14          = (float*)alloc((size_t)NODES * INDIM * 4);
    __hip_bfloat16* pooled = (__hip_bfloat16*)alloc((size_t)GRAPHS * HID * 2);
    __hip_bfloat16* Wt1b = (__hip_bfloat16*)alloc(HID * HID * 2);
    __hip_bfloat16* Wt2a = (__hip_bfloat16*)alloc(HID * HID * 2);
    __hip_bfloat16* Wt2b = (__hip_bfloat16*)alloc(HID * HID * 2);
    __hip_bfloat16* Wtout = (__hip_bfloat16*)alloc(HID * HID * 2);
    int* deg = (int*)alloc((size_t)NODES * 4);
    int* off = (int*)alloc((size_t)(NODES + 1) * 4);
    int* csr = (int*)alloc((size_t)EDGES * 4);
    int* partials = (int*)alloc(SCAN_BLK * 4);
    int* pref = (int*)alloc(SCAN_BLK * 4);
    float* out = (float*)d_out;

    const int nb_gemm = (NODES + 63) / 64;  // 1563

    // ---- weight conversion (bf16, transposed) ----
    k_w_cvt<<<64, 256, 0, stream>>>(W1b, Wt1b);
    k_w_cvt<<<64, 256, 0, stream>>>(W2a, Wt2a);
    k_w_cvt<<<64, 256, 0, stream>>>(W2b, Wt2b);
    k_w_cvt<<<64, 256, 0, stream>>>(Wout, Wtout);

    // ---- CSR build ----
    k_zero_int<<<(NODES + 255) / 256, 256, 0, stream>>>(deg, NODES);
    k_hist<<<(EDGES + 255) / 256, 256, 0, stream>>>(dst, deg);
    k_scan1<<<SCAN_BLK, 1024, 0, stream>>>(deg, partials);
    k_scan2<<<1, 128, 0, stream>>>(partials, pref);
    k_scan3<<<SCAN_BLK, 1024, 0, stream>>>(deg, pref, off);
    k_zero_int<<<(NODES + 255) / 256, 256, 0, stream>>>(deg, NODES);  // cursor
    k_fill<<<(EDGES + 255) / 256, 256, 0, stream>>>(src, dst, off, deg, csr);

    // ---- layer 1 ----
    k_gather14<<<(NODES * 16 + 255) / 256, 256, 0, stream>>>(x, off, csr, P14);
    k_gemm14_relu<<<(NODES * 32) / 256, 256, 0, stream>>>(P14, W1a, b1a, (unsigned*)Abf);
    k_mfma_gemm<1, 1><<<nb_gemm, 256, 0, stream>>>(Abf, Wt1b, b1b, Bbf, NODES);  // h1 -> Bbf

    // ---- layer 2 ----
    k_gather128_bf<<<(NODES + 3) / 4, 256, 0, stream>>>((const unsigned*)Bbf, off, csr,
                                                        (unsigned*)Abf);
    k_mfma_gemm<1, 1><<<nb_gemm, 256, 0, stream>>>(Abf, Wt2a, b2a, Bbf, NODES);
    k_mfma_gemm<1, 1><<<nb_gemm, 256, 0, stream>>>(Bbf, Wt2b, b2b, Abf, NODES);  // h2 -> Abf

    // ---- pool + head ----
    k_pool<<<GRAPHS, 128, 0, stream>>>(Abf, batch, pooled);
    k_mfma_gemm<0, 0><<<GRAPHS / 64, 256, 0, stream>>>(pooled, Wtout, bout, out, GRAPHS);
}

// Round 6
// 430.453 us; speedup vs baseline: 7.1317x; 1.1550x over previous
//
#include <hip/hip_runtime.h>
#include <hip/hip_bf16.h>

#define NODES  100000
#define EDGES  1600000
#define GRAPHS 4096
#define HID    128
#define INDIM  14
#define SCAN_BLK ((NODES + 1023) / 1024)  // 98
#define NPART  8
#define PART_SZ ((NODES + NPART - 1) / NPART)  // 12500
#define BPG    256  // blocks per partition group

typedef float f32x4 __attribute__((ext_vector_type(4)));
typedef short bf16x8 __attribute__((ext_vector_type(8)));

__device__ __forceinline__ unsigned packbf(float a, float b) {
    __hip_bfloat162 t;
    t.x = __float2bfloat16(a);
    t.y = __float2bfloat16(b);
    return *(unsigned*)&t;
}
__device__ __forceinline__ void acc8(float* a, uint4 v) {
    a[0] += __uint_as_float(v.x << 16);
    a[1] += __uint_as_float(v.x & 0xffff0000u);
    a[2] += __uint_as_float(v.y << 16);
    a[3] += __uint_as_float(v.y & 0xffff0000u);
    a[4] += __uint_as_float(v.z << 16);
    a[5] += __uint_as_float(v.z & 0xffff0000u);
    a[6] += __uint_as_float(v.w << 16);
    a[7] += __uint_as_float(v.w & 0xffff0000u);
}

// ---------------- CSR build (XCD-range-partitioned hist/fill) ----------------

__global__ void k_zero_int(int* __restrict__ p, int n) {
    int i = blockIdx.x * 256 + threadIdx.x;
    if (i < n) p[i] = 0;
}

// group g = blockIdx.x % NPART handles dst range [g*PART_SZ, (g+1)*PART_SZ);
// round-robin dispatch keeps each group's atomics/writes on one XCD's L2.
__global__ __launch_bounds__(256) void k_hist_p(const int* __restrict__ dst,
                                                int* __restrict__ deg) {
    const int g = blockIdx.x & (NPART - 1);
    const int blk = blockIdx.x >> 3;
    const int lo = g * PART_SZ;
    for (int e = blk * 256 + threadIdx.x; e < EDGES; e += BPG * 256) {
        int d = dst[e];
        if ((unsigned)(d - lo) < PART_SZ) atomicAdd(&deg[d], 1);
    }
}

__global__ __launch_bounds__(256) void k_fill_p(const int* __restrict__ src,
                                                const int* __restrict__ dst,
                                                const int* __restrict__ off,
                                                int* __restrict__ cnt,
                                                int* __restrict__ csr) {
    const int g = blockIdx.x & (NPART - 1);
    const int blk = blockIdx.x >> 3;
    const int lo = g * PART_SZ;
    for (int e = blk * 256 + threadIdx.x; e < EDGES; e += BPG * 256) {
        int d = dst[e];
        if ((unsigned)(d - lo) < PART_SZ) {
            int pos = off[d] + atomicAdd(&cnt[d], 1);
            csr[pos] = src[e];
        }
    }
}

__global__ __launch_bounds__(1024) void k_scan1(const int* __restrict__ deg,
                                                int* __restrict__ partials) {
    __shared__ int s[1024];
    int t = threadIdx.x;
    int i = blockIdx.x * 1024 + t;
    s[t] = (i < NODES) ? deg[i] : 0;
    __syncthreads();
    for (int o = 512; o > 0; o >>= 1) {
        if (t < o) s[t] += s[t + o];
        __syncthreads();
    }
    if (t == 0) partials[blockIdx.x] = s[0];
}

__global__ __launch_bounds__(128) void k_scan2(const int* __restrict__ partials,
                                               int* __restrict__ pref) {
    __shared__ int s[128];
    int t = threadIdx.x;
    int v = (t < SCAN_BLK) ? partials[t] : 0;
    s[t] = v;
    __syncthreads();
    for (int o = 1; o < 128; o <<= 1) {
        int u = (t >= o) ? s[t - o] : 0;
        __syncthreads();
        s[t] += u;
        __syncthreads();
    }
    if (t < SCAN_BLK) pref[t] = s[t] - v;
}

__global__ __launch_bounds__(1024) void k_scan3(const int* __restrict__ deg,
                                                const int* __restrict__ pref,
                                                int* __restrict__ off) {
    __shared__ int s[1024];
    int t = threadIdx.x;
    int i = blockIdx.x * 1024 + t;
    int v = (i < NODES) ? deg[i] : 0;
    s[t] = v;
    __syncthreads();
    for (int o = 1; o < 1024; o <<= 1) {
        int u = (t >= o) ? s[t - o] : 0;
        __syncthreads();
        s[t] += u;
        __syncthreads();
    }
    if (i < NODES) off[i] = pref[blockIdx.x] + s[t] - v;
    if (blockIdx.x == 0 && t == 0) off[NODES] = EDGES;
}

// ---------------- weight convert: W[k][n] fp32 -> Wt[n][k] bf16 ----------------

__global__ void k_w_cvt(const float* __restrict__ W, __hip_bfloat16* __restrict__ Wt) {
    int idx = blockIdx.x * 256 + threadIdx.x;  // 16384
    int n = idx & 127, k = idx >> 7;
    Wt[n * HID + k] = __float2bfloat16(W[k * HID + n]);
}

// ---------------- aggregation ----------------

__global__ void k_gather14(const float* __restrict__ x, const int* __restrict__ off,
                           const int* __restrict__ csr, float* __restrict__ P) {
    int idx = blockIdx.x * 256 + threadIdx.x;
    int n = idx >> 4, d = idx & 15;
    if (n >= NODES || d >= INDIM) return;
    int lo = off[n], hi = off[n + 1];
    float acc = x[n * INDIM + d];
    int e = lo;
    for (; e + 3 < hi; e += 4) {
        int s0 = csr[e], s1 = csr[e + 1], s2 = csr[e + 2], s3 = csr[e + 3];
        acc += x[s0 * INDIM + d] + x[s1 * INDIM + d] + x[s2 * INDIM + d] + x[s3 * INDIM + d];
    }
    for (; e < hi; e++) acc += x[csr[e] * INDIM + d];
    P[n * INDIM + d] = acc;
}

// 16 lanes x uint4 (16B) per 256B row -> 4 nodes/wave; unroll 4 edges in flight.
__global__ __launch_bounds__(256) void k_gather128_bf(const uint4* __restrict__ H,
                                                      const int* __restrict__ off,
                                                      const int* __restrict__ csr,
                                                      uint4* __restrict__ Out) {
    int node = (blockIdx.x * 256 + threadIdx.x) >> 4;
    int q = threadIdx.x & 15;
    if (node >= NODES) return;
    int lo = off[node], hi = off[node + 1];
    float a[8];
    {
        uint4 v = H[(size_t)node * 16 + q];
        a[0] = __uint_as_float(v.x << 16);
        a[1] = __uint_as_float(v.x & 0xffff0000u);
        a[2] = __uint_as_float(v.y << 16);
        a[3] = __uint_as_float(v.y & 0xffff0000u);
        a[4] = __uint_as_float(v.z << 16);
        a[5] = __uint_as_float(v.z & 0xffff0000u);
        a[6] = __uint_as_float(v.w << 16);
        a[7] = __uint_as_float(v.w & 0xffff0000u);
    }
    int e = lo;
    for (; e + 3 < hi; e += 4) {
        int s0 = csr[e], s1 = csr[e + 1], s2 = csr[e + 2], s3 = csr[e + 3];
        uint4 v0 = H[(size_t)s0 * 16 + q];
        uint4 v1 = H[(size_t)s1 * 16 + q];
        uint4 v2 = H[(size_t)s2 * 16 + q];
        uint4 v3 = H[(size_t)s3 * 16 + q];
        acc8(a, v0);
        acc8(a, v1);
        acc8(a, v2);
        acc8(a, v3);
    }
    for (; e < hi; e++) {
        uint4 v = H[(size_t)csr[e] * 16 + q];
        acc8(a, v);
    }
    uint4 o;
    o.x = packbf(a[0], a[1]);
    o.y = packbf(a[2], a[3]);
    o.z = packbf(a[4], a[5]);
    o.w = packbf(a[6], a[7]);
    Out[(size_t)node * 16 + q] = o;
}

// ---------------- layer-1 input GEMM (K=14, fp32 in, bf16 out) ----------------

__global__ __launch_bounds__(256) void k_gemm14_relu(const float* __restrict__ in,
                                                     const float* __restrict__ W,
                                                     const float* __restrict__ b,
                                                     unsigned* __restrict__ out) {
    int idx = blockIdx.x * 256 + threadIdx.x;
    int row = idx >> 5, c4 = (idx & 31) << 2;
    if (row >= NODES) return;
    const float4 bv = *(const float4*)&b[c4];
    float ax = bv.x, ay = bv.y, az = bv.z, aw = bv.w;
#pragma unroll
    for (int k = 0; k < INDIM; k++) {
        float a = in[row * INDIM + k];
        float4 w = *(const float4*)&W[k * HID + c4];
        ax += a * w.x; ay += a * w.y; az += a * w.z; aw += a * w.w;
    }
    unsigned p0 = packbf(fmaxf(ax, 0.f), fmaxf(ay, 0.f));
    unsigned p1 = packbf(fmaxf(az, 0.f), fmaxf(aw, 0.f));
    *(uint2*)&out[(size_t)row * 64 + (c4 >> 1)] = make_uint2(p0, p1);
}

// ---------------- MFMA GEMM: [M][128] bf16 @ Wt[n][k] bf16 + bias -> out ----------------

template <int RELU, int OUT_BF16>
__global__ __launch_bounds__(256) void k_mfma_gemm(const __hip_bfloat16* __restrict__ A,
                                                   const __hip_bfloat16* __restrict__ Wt,
                                                   const float* __restrict__ bias,
                                                   void* __restrict__ outv, int M) {
    const int wave = threadIdx.x >> 6;
    const int lane = threadIdx.x & 63;
    const int row0 = blockIdx.x * 64 + wave * 16;
    const int rl = lane & 15;
    const int kb = lane >> 4;  // 0..3

    int arow = row0 + rl;
    if (arow > M - 1) arow = M - 1;
    const __hip_bfloat16* Ap = A + (size_t)arow * HID + kb * 8;
    bf16x8 afrag[4];
#pragma unroll
    for (int kc = 0; kc < 4; kc++) afrag[kc] = *(const bf16x8*)(Ap + kc * 32);

    f32x4 acc[8];
#pragma unroll
    for (int n = 0; n < 8; n++) acc[n] = (f32x4){0.f, 0.f, 0.f, 0.f};

#pragma unroll
    for (int n = 0; n < 8; n++) {
        const __hip_bfloat16* Bp = Wt + (size_t)(n * 16 + rl) * HID + kb * 8;
#pragma unroll
        for (int kc = 0; kc < 4; kc++) {
            bf16x8 bfrag = *(const bf16x8*)(Bp + kc * 32);
            acc[n] = __builtin_amdgcn_mfma_f32_16x16x32_bf16(afrag[kc], bfrag, acc[n], 0, 0, 0);
        }
    }

#pragma unroll
    for (int n = 0; n < 8; n++) {
        const int col = n * 16 + rl;
        const float bv = bias[col];
#pragma unroll
        for (int j = 0; j < 4; j++) {
            int row = row0 + kb * 4 + j;
            if (row < M) {
                float v = acc[n][j] + bv;
                if (RELU) v = fmaxf(v, 0.f);
                if (OUT_BF16)
                    ((__hip_bfloat16*)outv)[(size_t)row * HID + col] = __float2bfloat16(v);
                else
                    ((float*)outv)[(size_t)row * HID + col] = v;
            }
        }
    }
}

// ---------------- mean pool (bf16 in, bf16 out) ----------------

__device__ __forceinline__ int lower_bound_i(const int* __restrict__ a, int n, int key) {
    int lo = 0, hi = n;
    while (lo < hi) {
        int mid = (lo + hi) >> 1;
        if (a[mid] < key) lo = mid + 1; else hi = mid;
    }
    return lo;
}

__global__ __launch_bounds__(128) void k_pool(const __hip_bfloat16* __restrict__ H,
                                              const int* __restrict__ batch,
                                              __hip_bfloat16* __restrict__ pooled) {
    int g = blockIdx.x;
    int d = threadIdx.x;
    int lo = lower_bound_i(batch, NODES, g);
    int hi = lower_bound_i(batch, NODES, g + 1);
    float acc = 0.f;
    for (int i = lo; i < hi; i++) acc += __bfloat162float(H[(size_t)i * HID + d]);
    float cnt = (float)(hi - lo);
    pooled[(size_t)g * HID + d] = __float2bfloat16(acc / fmaxf(cnt, 1.0f));
}

// ---------------- launch ----------------

extern "C" void kernel_launch(void* const* d_in, const int* in_sizes, int n_in,
                              void* d_out, int out_size, void* d_ws, size_t ws_size,
                              hipStream_t stream) {
    const float* x     = (const float*)d_in[0];
    const int*   ei    = (const int*)d_in[1];
    const int*   batch = (const int*)d_in[2];
    const float* W1a = (const float*)d_in[3];
    const float* b1a = (const float*)d_in[4];
    const float* W1b = (const float*)d_in[5];
    const float* b1b = (const float*)d_in[6];
    const float* W2a = (const float*)d_in[7];
    const float* b2a = (const float*)d_in[8];
    const float* W2b = (const float*)d_in[9];
    const float* b2b = (const float*)d_in[10];
    const float* Wout = (const float*)d_in[11];
    const float* bout = (const float*)d_in[12];

    const int* src = ei;
    const int* dst = ei + EDGES;

    char* w = (char*)d_ws;
    auto alloc = [&](size_t bytes) {
        void* p = (void*)w;
        w += (bytes + 255) & ~(size_t)255;
        return p;
    };
    __hip_bfloat16* Abf = (__hip_bfloat16*)alloc((size_t)NODES * HID * 2);
    __hip_bfloat16* Bbf = (__hip_bfloat16*)alloc((size_t)NODES * HID * 2);
    float* P14          = (float*)alloc((size_t)NODES * INDIM * 4);
    __hip_bfloat16* pooled = (__hip_bfloat16*)alloc((size_t)GRAPHS * HID * 2);
    __hip_bfloat16* Wt1b = (__hip_bfloat16*)alloc(HID * HID * 2);
    __hip_bfloat16* Wt2a = (__hip_bfloat16*)alloc(HID * HID * 2);
    __hip_bfloat16* Wt2b = (__hip_bfloat16*)alloc(HID * HID * 2);
    __hip_bfloat16* Wtout = (__hip_bfloat16*)alloc(HID * HID * 2);
    int* deg = (int*)alloc((size_t)NODES * 4);
    int* off = (int*)alloc((size_t)(NODES + 1) * 4);
    int* csr = (int*)alloc((size_t)EDGES * 4);
    int* partials = (int*)alloc(SCAN_BLK * 4);
    int* pref = (int*)alloc(SCAN_BLK * 4);
    float* out = (float*)d_out;

    const int nb_gemm = (NODES + 63) / 64;  // 1563

    // ---- weight conversion (bf16, transposed) ----
    k_w_cvt<<<64, 256, 0, stream>>>(W1b, Wt1b);
    k_w_cvt<<<64, 256, 0, stream>>>(W2a, Wt2a);
    k_w_cvt<<<64, 256, 0, stream>>>(W2b, Wt2b);
    k_w_cvt<<<64, 256, 0, stream>>>(Wout, Wtout);

    // ---- CSR build ----
    k_zero_int<<<(NODES + 255) / 256, 256, 0, stream>>>(deg, NODES);
    k_hist_p<<<NPART * BPG, 256, 0, stream>>>(dst, deg);
    k_scan1<<<SCAN_BLK, 1024, 0, stream>>>(deg, partials);
    k_scan2<<<1, 128, 0, stream>>>(partials, pref);
    k_scan3<<<SCAN_BLK, 1024, 0, stream>>>(deg, pref, off);
    k_zero_int<<<(NODES + 255) / 256, 256, 0, stream>>>(deg, NODES);  // cursor
    k_fill_p<<<NPART * BPG, 256, 0, stream>>>(src, dst, off, deg, csr);

    // ---- layer 1 ----
    k_gather14<<<(NODES * 16 + 255) / 256, 256, 0, stream>>>(x, off, csr, P14);
    k_gemm14_relu<<<(NODES * 32) / 256, 256, 0, stream>>>(P14, W1a, b1a, (unsigned*)Abf);
    k_mfma_gemm<1, 1><<<nb_gemm, 256, 0, stream>>>(Abf, Wt1b, b1b, Bbf, NODES);  // h1 -> Bbf

    // ---- layer 2 ----
    k_gather128_bf<<<(NODES * 16 + 255) / 256, 256, 0, stream>>>((const uint4*)Bbf, off, csr,
                                                                 (uint4*)Abf);
    k_mfma_gemm<1, 1><<<nb_gemm, 256, 0, stream>>>(Abf, Wt2a, b2a, Bbf, NODES);
    k_mfma_gemm<1, 1><<<nb_gemm, 256, 0, stream>>>(Bbf, Wt2b, b2b, Abf, NODES);  // h2 -> Abf

    // ---- pool + head ----
    k_pool<<<GRAPHS, 128, 0, stream>>>(Abf, batch, pooled);
    k_mfma_gemm<0, 0><<<GRAPHS / 64, 256, 0, stream>>>(pooled, Wtout, bout, out, GRAPHS);
}

// Round 7
// 418.023 us; speedup vs baseline: 7.3438x; 1.0297x over previous
//
#include <hip/hip_runtime.h>
#include <hip/hip_bf16.h>

#define NODES  100000
#define EDGES  1600000
#define GRAPHS 4096
#define HID    128
#define INDIM  14
#define SCAN_BLK ((NODES + 1023) / 1024)  // 98
#define NPART  8
#define PART_SZ ((NODES + NPART - 1) / NPART)  // 12500
#define BPG    256  // blocks per partition group
#define LDST   136  // LDS tile row stride in bf16 (272B: 16B-aligned, conflict-light)

typedef float f32x4 __attribute__((ext_vector_type(4)));
typedef short bf16x8 __attribute__((ext_vector_type(8)));

__device__ __forceinline__ unsigned packbf(float a, float b) {
    __hip_bfloat162 t;
    t.x = __float2bfloat16(a);
    t.y = __float2bfloat16(b);
    return *(unsigned*)&t;
}
__device__ __forceinline__ void acc8(float* a, uint4 v) {
    a[0] += __uint_as_float(v.x << 16);
    a[1] += __uint_as_float(v.x & 0xffff0000u);
    a[2] += __uint_as_float(v.y << 16);
    a[3] += __uint_as_float(v.y & 0xffff0000u);
    a[4] += __uint_as_float(v.z << 16);
    a[5] += __uint_as_float(v.z & 0xffff0000u);
    a[6] += __uint_as_float(v.w << 16);
    a[7] += __uint_as_float(v.w & 0xffff0000u);
}

// ---------------- CSR build (XCD-range-partitioned hist/fill) ----------------

__global__ void k_zero_int(int* __restrict__ p, int n) {
    int i = blockIdx.x * 256 + threadIdx.x;
    if (i < n) p[i] = 0;
}

__global__ __launch_bounds__(256) void k_hist_p(const int* __restrict__ dst,
                                                int* __restrict__ deg) {
    const int g = blockIdx.x & (NPART - 1);
    const int blk = blockIdx.x >> 3;
    const int lo = g * PART_SZ;
    for (int e = blk * 256 + threadIdx.x; e < EDGES; e += BPG * 256) {
        int d = dst[e];
        if ((unsigned)(d - lo) < PART_SZ) atomicAdd(&deg[d], 1);
    }
}

__global__ __launch_bounds__(256) void k_fill_p(const int* __restrict__ src,
                                                const int* __restrict__ dst,
                                                const int* __restrict__ off,
                                                int* __restrict__ cnt,
                                                int* __restrict__ csr) {
    const int g = blockIdx.x & (NPART - 1);
    const int blk = blockIdx.x >> 3;
    const int lo = g * PART_SZ;
    for (int e = blk * 256 + threadIdx.x; e < EDGES; e += BPG * 256) {
        int d = dst[e];
        if ((unsigned)(d - lo) < PART_SZ) {
            int pos = off[d] + atomicAdd(&cnt[d], 1);
            csr[pos] = src[e];
        }
    }
}

__global__ __launch_bounds__(1024) void k_scan1(const int* __restrict__ deg,
                                                int* __restrict__ partials) {
    __shared__ int s[1024];
    int t = threadIdx.x;
    int i = blockIdx.x * 1024 + t;
    s[t] = (i < NODES) ? deg[i] : 0;
    __syncthreads();
    for (int o = 512; o > 0; o >>= 1) {
        if (t < o) s[t] += s[t + o];
        __syncthreads();
    }
    if (t == 0) partials[blockIdx.x] = s[0];
}

__global__ __launch_bounds__(128) void k_scan2(const int* __restrict__ partials,
                                               int* __restrict__ pref) {
    __shared__ int s[128];
    int t = threadIdx.x;
    int v = (t < SCAN_BLK) ? partials[t] : 0;
    s[t] = v;
    __syncthreads();
    for (int o = 1; o < 128; o <<= 1) {
        int u = (t >= o) ? s[t - o] : 0;
        __syncthreads();
        s[t] += u;
        __syncthreads();
    }
    if (t < SCAN_BLK) pref[t] = s[t] - v;
}

__global__ __launch_bounds__(1024) void k_scan3(const int* __restrict__ deg,
                                                const int* __restrict__ pref,
                                                int* __restrict__ off) {
    __shared__ int s[1024];
    int t = threadIdx.x;
    int i = blockIdx.x * 1024 + t;
    int v = (i < NODES) ? deg[i] : 0;
    s[t] = v;
    __syncthreads();
    for (int o = 1; o < 1024; o <<= 1) {
        int u = (t >= o) ? s[t - o] : 0;
        __syncthreads();
        s[t] += u;
        __syncthreads();
    }
    if (i < NODES) off[i] = pref[blockIdx.x] + s[t] - v;
    if (blockIdx.x == 0 && t == 0) off[NODES] = EDGES;
}

// ---------------- weight convert: 4x W[k][n] fp32 -> Wt[n][k] bf16 ----------------

__global__ void k_w_cvt4(const float* __restrict__ Wa, const float* __restrict__ Wb,
                         const float* __restrict__ Wc, const float* __restrict__ Wd,
                         __hip_bfloat16* __restrict__ Ta, __hip_bfloat16* __restrict__ Tb,
                         __hip_bfloat16* __restrict__ Tc, __hip_bfloat16* __restrict__ Td) {
    int which = blockIdx.x >> 6;
    int idx = (blockIdx.x & 63) * 256 + threadIdx.x;  // 16384 per matrix
    const float* W = which == 0 ? Wa : which == 1 ? Wb : which == 2 ? Wc : Wd;
    __hip_bfloat16* T = which == 0 ? Ta : which == 1 ? Tb : which == 2 ? Tc : Td;
    int n = idx & 127, k = idx >> 7;
    T[n * HID + k] = __float2bfloat16(W[k * HID + n]);
}

// ---------------- shared MFMA tile step: [64][LDST] bf16 LDS @ Wt + bias ----------------
// A frag: lane holds in[wave*16 + (l&15)][kb*8 + kc*32 .. +7]; C/D: col=l&15(+16n), row=kb*4+j.
template <int RELU, int TO_LDS>
__device__ __forceinline__ void mfma_tile(const __hip_bfloat16* lds_in,
                                          const __hip_bfloat16* __restrict__ Wt,
                                          const float* __restrict__ bias,
                                          __hip_bfloat16* lds_out,
                                          __hip_bfloat16* __restrict__ gout,
                                          int row0, int M, int tid) {
    const int wave = tid >> 6;
    const int lane = tid & 63;
    const int rl = lane & 15;
    const int kb = lane >> 4;

    const __hip_bfloat16* Ap = lds_in + (wave * 16 + rl) * LDST + kb * 8;
    bf16x8 afrag[4];
#pragma unroll
    for (int kc = 0; kc < 4; kc++) afrag[kc] = *(const bf16x8*)(Ap + kc * 32);

    f32x4 acc[8];
#pragma unroll
    for (int n = 0; n < 8; n++) acc[n] = (f32x4){0.f, 0.f, 0.f, 0.f};

#pragma unroll
    for (int n = 0; n < 8; n++) {
        const __hip_bfloat16* Bp = Wt + (size_t)(n * 16 + rl) * HID + kb * 8;
#pragma unroll
        for (int kc = 0; kc < 4; kc++) {
            bf16x8 bfrag = *(const bf16x8*)(Bp + kc * 32);
            acc[n] = __builtin_amdgcn_mfma_f32_16x16x32_bf16(afrag[kc], bfrag, acc[n], 0, 0, 0);
        }
    }

#pragma unroll
    for (int n = 0; n < 8; n++) {
        const int col = n * 16 + rl;
        const float bv = bias[col];
#pragma unroll
        for (int j = 0; j < 4; j++) {
            int rloc = wave * 16 + kb * 4 + j;
            float v = acc[n][j] + bv;
            if (RELU) v = fmaxf(v, 0.f);
            if (TO_LDS) {
                lds_out[rloc * LDST + col] = __float2bfloat16(v);
            } else {
                int row = row0 + rloc;
                if (row < M) gout[(size_t)row * HID + col] = __float2bfloat16(v);
            }
        }
    }
}

// ---------------- layer 1 fused: gather14 + K=14 GEMM + MFMA(W1b) -> h1 ----------------

__global__ __launch_bounds__(256) void k_l1(const float* __restrict__ x,
                                            const int* __restrict__ off,
                                            const int* __restrict__ csr,
                                            const float* __restrict__ W1a,
                                            const float* __restrict__ b1a,
                                            const __hip_bfloat16* __restrict__ Wt1b,
                                            const float* __restrict__ b1b,
                                            __hip_bfloat16* __restrict__ h1) {
    __shared__ float p14[64][16];
    __shared__ __hip_bfloat16 t[64 * LDST];
    const int row0 = blockIdx.x * 64;
    const int tid = threadIdx.x;

    // phase 1: gather x + neighbor sum (16 threads/node, 14 active)
    for (int task = tid; task < 1024; task += 256) {
        int n = task >> 4, d = task & 15;
        int node = row0 + n;
        if (node < NODES && d < INDIM) {
            int lo = off[node], hi = off[node + 1];
            float acc = x[node * INDIM + d];
            int e = lo;
            for (; e + 3 < hi; e += 4) {
                int s0 = csr[e], s1 = csr[e + 1], s2 = csr[e + 2], s3 = csr[e + 3];
                acc += x[s0 * INDIM + d] + x[s1 * INDIM + d] +
                       x[s2 * INDIM + d] + x[s3 * INDIM + d];
            }
            for (; e < hi; e++) acc += x[csr[e] * INDIM + d];
            p14[n][d] = acc;
        }
    }
    __syncthreads();

    // phase 2: K=14 VALU GEMM + relu -> bf16 LDS tile
    for (int i = tid; i < 2048; i += 256) {
        int r = i >> 5, c4 = (i & 31) << 2;
        float4 bv = *(const float4*)&b1a[c4];
        float ax = bv.x, ay = bv.y, az = bv.z, aw = bv.w;
#pragma unroll
        for (int k = 0; k < INDIM; k++) {
            float a = p14[r][k];
            float4 w = *(const float4*)&W1a[k * HID + c4];
            ax += a * w.x; ay += a * w.y; az += a * w.z; aw += a * w.w;
        }
        unsigned p0 = packbf(fmaxf(ax, 0.f), fmaxf(ay, 0.f));
        unsigned p1 = packbf(fmaxf(az, 0.f), fmaxf(aw, 0.f));
        *(uint2*)&t[r * LDST + c4] = make_uint2(p0, p1);
    }
    __syncthreads();

    // phase 3: MFMA x Wt1b -> h1
    mfma_tile<1, 0>(t, Wt1b, b1b, nullptr, h1, row0, NODES, tid);
}

// ---------------- layer 2 fused: gather128(h1) + MFMA(W2a) + MFMA(W2b) -> h2 ----------------

__global__ __launch_bounds__(256) void k_l2(const uint4* __restrict__ H,
                                            const int* __restrict__ off,
                                            const int* __restrict__ csr,
                                            const __hip_bfloat16* __restrict__ Wt2a,
                                            const float* __restrict__ b2a,
                                            const __hip_bfloat16* __restrict__ Wt2b,
                                            const float* __restrict__ b2b,
                                            __hip_bfloat16* __restrict__ h2) {
    __shared__ __hip_bfloat16 agg[64 * LDST];
    __shared__ __hip_bfloat16 t2[64 * LDST];
    const int row0 = blockIdx.x * 64;
    const int tid = threadIdx.x;

    // phase 1: neighbor-sum gather of h1 rows (16 lanes x uint4 per row, unroll 4)
    for (int task = tid; task < 1024; task += 256) {
        int n = task >> 4, q = task & 15;
        int node = row0 + n;
        if (node < NODES) {
            int lo = off[node], hi = off[node + 1];
            float a[8];
            uint4 v = H[(size_t)node * 16 + q];
            a[0] = __uint_as_float(v.x << 16);
            a[1] = __uint_as_float(v.x & 0xffff0000u);
            a[2] = __uint_as_float(v.y << 16);
            a[3] = __uint_as_float(v.y & 0xffff0000u);
            a[4] = __uint_as_float(v.z << 16);
            a[5] = __uint_as_float(v.z & 0xffff0000u);
            a[6] = __uint_as_float(v.w << 16);
            a[7] = __uint_as_float(v.w & 0xffff0000u);
            int e = lo;
            for (; e + 3 < hi; e += 4) {
                int s0 = csr[e], s1 = csr[e + 1], s2 = csr[e + 2], s3 = csr[e + 3];
                uint4 v0 = H[(size_t)s0 * 16 + q];
                uint4 v1 = H[(size_t)s1 * 16 + q];
                uint4 v2 = H[(size_t)s2 * 16 + q];
                uint4 v3 = H[(size_t)s3 * 16 + q];
                acc8(a, v0); acc8(a, v1); acc8(a, v2); acc8(a, v3);
            }
            for (; e < hi; e++) {
                uint4 vv = H[(size_t)csr[e] * 16 + q];
                acc8(a, vv);
            }
            uint4 o;
            o.x = packbf(a[0], a[1]);
            o.y = packbf(a[2], a[3]);
            o.z = packbf(a[4], a[5]);
            o.w = packbf(a[6], a[7]);
            *(uint4*)&agg[n * LDST + q * 8] = o;
        }
    }
    __syncthreads();

    // phase 2: MFMA x Wt2a -> t2 (LDS)
    mfma_tile<1, 1>(agg, Wt2a, b2a, t2, nullptr, row0, NODES, tid);
    __syncthreads();

    // phase 3: MFMA x Wt2b -> h2 (global)
    mfma_tile<1, 0>(t2, Wt2b, b2b, nullptr, h2, row0, NODES, tid);
}

// ---------------- head GEMM (global A): pooled @ Wt + bias ----------------

template <int RELU, int OUT_BF16>
__global__ __launch_bounds__(256) void k_mfma_gemm(const __hip_bfloat16* __restrict__ A,
                                                   const __hip_bfloat16* __restrict__ Wt,
                                                   const float* __restrict__ bias,
                                                   void* __restrict__ outv, int M) {
    const int wave = threadIdx.x >> 6;
    const int lane = threadIdx.x & 63;
    const int row0 = blockIdx.x * 64 + wave * 16;
    const int rl = lane & 15;
    const int kb = lane >> 4;

    int arow = row0 + rl;
    if (arow > M - 1) arow = M - 1;
    const __hip_bfloat16* Ap = A + (size_t)arow * HID + kb * 8;
    bf16x8 afrag[4];
#pragma unroll
    for (int kc = 0; kc < 4; kc++) afrag[kc] = *(const bf16x8*)(Ap + kc * 32);

    f32x4 acc[8];
#pragma unroll
    for (int n = 0; n < 8; n++) acc[n] = (f32x4){0.f, 0.f, 0.f, 0.f};

#pragma unroll
    for (int n = 0; n < 8; n++) {
        const __hip_bfloat16* Bp = Wt + (size_t)(n * 16 + rl) * HID + kb * 8;
#pragma unroll
        for (int kc = 0; kc < 4; kc++) {
            bf16x8 bfrag = *(const bf16x8*)(Bp + kc * 32);
            acc[n] = __builtin_amdgcn_mfma_f32_16x16x32_bf16(afrag[kc], bfrag, acc[n], 0, 0, 0);
        }
    }

#pragma unroll
    for (int n = 0; n < 8; n++) {
        const int col = n * 16 + rl;
        const float bv = bias[col];
#pragma unroll
        for (int j = 0; j < 4; j++) {
            int row = row0 + kb * 4 + j;
            if (row < M) {
                float v = acc[n][j] + bv;
                if (RELU) v = fmaxf(v, 0.f);
                if (OUT_BF16)
                    ((__hip_bfloat16*)outv)[(size_t)row * HID + col] = __float2bfloat16(v);
                else
                    ((float*)outv)[(size_t)row * HID + col] = v;
            }
        }
    }
}

// ---------------- mean pool (bf16 in, bf16 out) ----------------

__device__ __forceinline__ int lower_bound_i(const int* __restrict__ a, int n, int key) {
    int lo = 0, hi = n;
    while (lo < hi) {
        int mid = (lo + hi) >> 1;
        if (a[mid] < key) lo = mid + 1; else hi = mid;
    }
    return lo;
}

__global__ __launch_bounds__(128) void k_pool(const __hip_bfloat16* __restrict__ H,
                                              const int* __restrict__ batch,
                                              __hip_bfloat16* __restrict__ pooled) {
    int g = blockIdx.x;
    int d = threadIdx.x;
    int lo = lower_bound_i(batch, NODES, g);
    int hi = lower_bound_i(batch, NODES, g + 1);
    float acc = 0.f;
    for (int i = lo; i < hi; i++) acc += __bfloat162float(H[(size_t)i * HID + d]);
    float cnt = (float)(hi - lo);
    pooled[(size_t)g * HID + d] = __float2bfloat16(acc / fmaxf(cnt, 1.0f));
}

// ---------------- launch ----------------

extern "C" void kernel_launch(void* const* d_in, const int* in_sizes, int n_in,
                              void* d_out, int out_size, void* d_ws, size_t ws_size,
                              hipStream_t stream) {
    const float* x     = (const float*)d_in[0];
    const int*   ei    = (const int*)d_in[1];
    const int*   batch = (const int*)d_in[2];
    const float* W1a = (const float*)d_in[3];
    const float* b1a = (const float*)d_in[4];
    const float* W1b = (const float*)d_in[5];
    const float* b1b = (const float*)d_in[6];
    const float* W2a = (const float*)d_in[7];
    const float* b2a = (const float*)d_in[8];
    const float* W2b = (const float*)d_in[9];
    const float* b2b = (const float*)d_in[10];
    const float* Wout = (const float*)d_in[11];
    const float* bout = (const float*)d_in[12];

    const int* src = ei;
    const int* dst = ei + EDGES;

    char* w = (char*)d_ws;
    auto alloc = [&](size_t bytes) {
        void* p = (void*)w;
        w += (bytes + 255) & ~(size_t)255;
        return p;
    };
    __hip_bfloat16* h1 = (__hip_bfloat16*)alloc((size_t)NODES * HID * 2);
    __hip_bfloat16* h2 = (__hip_bfloat16*)alloc((size_t)NODES * HID * 2);
    __hip_bfloat16* pooled = (__hip_bfloat16*)alloc((size_t)GRAPHS * HID * 2);
    __hip_bfloat16* Wt1b = (__hip_bfloat16*)alloc(HID * HID * 2);
    __hip_bfloat16* Wt2a = (__hip_bfloat16*)alloc(HID * HID * 2);
    __hip_bfloat16* Wt2b = (__hip_bfloat16*)alloc(HID * HID * 2);
    __hip_bfloat16* Wtout = (__hip_bfloat16*)alloc(HID * HID * 2);
    int* deg = (int*)alloc((size_t)NODES * 4);
    int* off = (int*)alloc((size_t)(NODES + 1) * 4);
    int* csr = (int*)alloc((size_t)EDGES * 4);
    int* partials = (int*)alloc(SCAN_BLK * 4);
    int* pref = (int*)alloc(SCAN_BLK * 4);
    float* out = (float*)d_out;

    const int nb = (NODES + 63) / 64;  // 1563

    // ---- weight conversion (bf16, transposed), one launch ----
    k_w_cvt4<<<256, 256, 0, stream>>>(W1b, W2a, W2b, Wout, Wt1b, Wt2a, Wt2b, Wtout);

    // ---- CSR build ----
    k_zero_int<<<(NODES + 255) / 256, 256, 0, stream>>>(deg, NODES);
    k_hist_p<<<NPART * BPG, 256, 0, stream>>>(dst, deg);
    k_scan1<<<SCAN_BLK, 1024, 0, stream>>>(deg, partials);
    k_scan2<<<1, 128, 0, stream>>>(partials, pref);
    k_scan3<<<SCAN_BLK, 1024, 0, stream>>>(deg, pref, off);
    k_zero_int<<<(NODES + 255) / 256, 256, 0, stream>>>(deg, NODES);  // cursor
    k_fill_p<<<NPART * BPG, 256, 0, stream>>>(src, dst, off, deg, csr);

    // ---- layer 1 (fused) ----
    k_l1<<<nb, 256, 0, stream>>>(x, off, csr, W1a, b1a, Wt1b, b1b, h1);

    // ---- layer 2 (fused) ----
    k_l2<<<nb, 256, 0, stream>>>((const uint4*)h1, off, csr, Wt2a, b2a, Wt2b, b2b, h2);

    // ---- pool + head ----
    k_pool<<<GRAPHS, 128, 0, stream>>>(h2, batch, pooled);
    k_mfma_gemm<0, 0><<<GRAPHS / 64, 256, 0, stream>>>(pooled, Wtout, bout, out, GRAPHS);
}